// Round 1
// baseline (407.835 us; speedup 1.0000x reference)
//
#include <hip/hip_runtime.h>
#include <hip/hip_bf16.h>
#include <stdint.h>

// VisionTransformerBlock on MI355X (gfx950).
// Pipeline: conv(x,W->bf16) -> QKV gemm -> attention -> Wo gemm -> LN1+res+relu
//           -> merged Wd gemm -> LN2+relu -> d_out (f32).
// d_ws layout (bytes), SEG = 50331648:
//   [0*SEG)      x_bf16  (later: attn-out z)
//   [1*SEG)      q [bm,h,p,a]          (later: y1 = z@Wo+bo, bf16)
//   [2*SEG)      k [bm,h,p,a]          (later: z2 = relu(x+LN1), bf16)
//   [3*SEG)      v^T [bm,h,a,p]        (later: y2 = merged@Wd+bd, f32)
//   [4*SEG)      wqkv_t[1536][512] | wo_t[512][512] | wd_t[512][1024] | bqkv f32[1536]
// total ~204.5 MB.

typedef __hip_bfloat16 bf16;
typedef __attribute__((ext_vector_type(8))) __bf16 bf16v8;
typedef __attribute__((ext_vector_type(4))) float f32x4;
typedef __attribute__((ext_vector_type(8))) short s16x8;
typedef __attribute__((ext_vector_type(4))) short s16x4;

static __device__ __forceinline__ void gl_lds16(const void* src, void* dst) {
  __builtin_amdgcn_global_load_lds((const __attribute__((address_space(1))) void*)src,
                                   (__attribute__((address_space(3))) void*)dst,
                                   16, 0, 0);
}

static __device__ __forceinline__ unsigned short f2bfu(float f) {
  return __builtin_bit_cast(unsigned short, __float2bfloat16(f));
}
static __device__ __forceinline__ float bfu2f(unsigned short u) {
  return __builtin_bit_cast(float, (unsigned int)u << 16);
}

// ------------------------- conversions -------------------------
__global__ __launch_bounds__(256) void conv_x_kernel(const float4* __restrict__ x,
                                                     s16x4* __restrict__ xb, int n4) {
  int stride = gridDim.x * 256;
  for (int i = blockIdx.x * 256 + threadIdx.x; i < n4; i += stride) {
    float4 v = x[i];
    s16x4 o;
    o[0] = (short)f2bfu(v.x); o[1] = (short)f2bfu(v.y);
    o[2] = (short)f2bfu(v.z); o[3] = (short)f2bfu(v.w);
    xb[i] = o;
  }
}

__global__ __launch_bounds__(256) void conv_w_kernel(
    const float* __restrict__ Wq, const float* __restrict__ Wk, const float* __restrict__ Wv,
    const float* __restrict__ Wo, const float* __restrict__ Wd,
    const float* __restrict__ bq, const float* __restrict__ bk, const float* __restrict__ bv,
    bf16* __restrict__ wqkv_t, bf16* __restrict__ wo_t, bf16* __restrict__ wd_t,
    float* __restrict__ bqkv) {
  int o = blockIdx.x * 256 + threadIdx.x;
  if (o < 786432) {                       // wqkv_t[j][kk], j in [0,1536)
    int j = o >> 9, kk = o & 511;
    const float* W = (j < 512) ? Wq : (j < 1024) ? Wk : Wv;
    wqkv_t[o] = __float2bfloat16(W[kk * 512 + (j & 511)]);
  } else if (o < 1048576) {               // wo_t[j][kk]
    int o2 = o - 786432; int j = o2 >> 9, kk = o2 & 511;
    wo_t[o2] = __float2bfloat16(Wo[kk * 512 + j]);
  } else if (o < 1572864) {               // wd_t[j][kk], kk in [0,1024)
    int o3 = o - 1048576; int j = o3 >> 10, kk = o3 & 1023;
    wd_t[o3] = __float2bfloat16(Wd[kk * 512 + j]);
  } else if (o < 1574400) {               // bqkv concat (f32)
    int o4 = o - 1572864;
    const float* b = (o4 < 512) ? bq : (o4 < 1024) ? bk : bv;
    bqkv[o4] = b[o4 & 511];
  }
}

// ------------------------- GEMM 128x128, BK=32 -------------------------
// A: bf16 row-major [M][K] (AMODE1: patch-merged view of z2 [49152][512]).
// Bt: bf16 [N][K]. LDS slabs [128 rows][32 k] with 16B-slot XOR swizzle
// (slot ^ (row&3)) applied on the global SOURCE (global_load_lds dest linear).
// EPI 0: qkv scatter; 1: bf16 row-major out; 2: f32 row-major out. ldc=512.
template<int EPI, int AMODE>
__global__ __launch_bounds__(256) void gemm128(
    const bf16* __restrict__ A, const bf16* __restrict__ Bt,
    const float* __restrict__ bias, int K,
    bf16* __restrict__ oq, bf16* __restrict__ ok, bf16* __restrict__ ovt,
    bf16* __restrict__ obf, float* __restrict__ of) {
  __shared__ __align__(16) char smem[16384];
  const int tid = threadIdx.x;
  const int wave = tid >> 6, lane = tid & 63;
  const int wr = wave >> 1, wc = wave & 1;
  const int lane15 = lane & 15, g = lane >> 4;
  const int tileM = blockIdx.x * 128, tileN = blockIdx.y * 128;
  const int sw = (lane & 3) << 4;

  int aoff[4], boff[4];
#pragma unroll
  for (int m = 0; m < 4; ++m)
    aoff[m] = (wr * 64 + m * 16 + lane15) * 64 + ((g * 16) ^ sw);
#pragma unroll
  for (int n = 0; n < 4; ++n)
    boff[n] = 8192 + (wc * 64 + n * 16 + lane15) * 64 + ((g * 16) ^ sw);

  f32x4 acc[4][4] = {};

  for (int k0 = 0; k0 < K; k0 += 32) {
#pragma unroll
    for (int i = 0; i < 2; ++i) {
      int s = wave * 128 + i * 64 + lane;   // wave-contiguous 16B slots
      int r = s >> 2;
      int kb = (s & 3) ^ (r & 3);           // inverse-swizzled source chunk
      const bf16* srcA;
      if (AMODE == 0) {
        srcA = A + (size_t)(tileM + r) * K + k0 + kb * 8;
      } else {                              // patch-merge view of z2[49152][512]
        int mr = tileM + r; int bm = mr >> 7, pp = mr & 127;
        int t = bm * 256 + pp * 2 + (k0 >> 9);
        srcA = A + (size_t)t * 512 + (k0 & 511) + kb * 8;
      }
      gl_lds16(srcA, smem + s * 16);
      const bf16* srcB = Bt + (size_t)(tileN + r) * K + k0 + kb * 8;
      gl_lds16(srcB, smem + 8192 + s * 16);
    }
    __syncthreads();
    bf16v8 af[4], bfr[4];
#pragma unroll
    for (int m = 0; m < 4; ++m) af[m] = *(const bf16v8*)(smem + aoff[m]);
#pragma unroll
    for (int n = 0; n < 4; ++n) bfr[n] = *(const bf16v8*)(smem + boff[n]);
#pragma unroll
    for (int m = 0; m < 4; ++m)
#pragma unroll
      for (int n = 0; n < 4; ++n)
        acc[m][n] = __builtin_amdgcn_mfma_f32_16x16x32_bf16(af[m], bfr[n], acc[m][n], 0, 0, 0);
    __syncthreads();
  }

#pragma unroll
  for (int m = 0; m < 4; ++m) {
#pragma unroll
    for (int n = 0; n < 4; ++n) {
      int col = tileN + wc * 64 + n * 16 + lane15;
      float bb = bias[col];
#pragma unroll
      for (int i = 0; i < 4; ++i) {
        int row = tileM + wr * 64 + m * 16 + g * 4 + i;
        float val = acc[m][n][i] + bb;
        if (EPI == 0) {
          int bm = row >> 8, p = row & 255;
          if (col < 512) {
            int hh = col >> 6, a = col & 63;
            oq[((size_t)(bm * 8 + hh) << 14) + (p << 6) + a] = __float2bfloat16(val);
          } else if (col < 1024) {
            int j = col - 512; int hh = j >> 6, a = j & 63;
            ok[((size_t)(bm * 8 + hh) << 14) + (p << 6) + a] = __float2bfloat16(val);
          } else {
            int j = col - 1024; int hh = j >> 6, a = j & 63;
            ovt[((size_t)(bm * 8 + hh) << 14) + (a << 8) + p] = __float2bfloat16(val);
          }
        } else if (EPI == 1) {
          obf[(size_t)row * 512 + col] = __float2bfloat16(val);
        } else {
          of[(size_t)row * 512 + col] = val;
        }
      }
    }
  }
}

// ------------------------- attention -------------------------
// Block = (qc, h, bm): 64 q-rows, 4 waves x 16 rows. LDS: K[256][64] (swz),
// Vt[64][256] (swz), P per-wave 16x128 bf16 round-trip slab (swz). 80 KB.
__global__ __launch_bounds__(256) void attn_kernel(const bf16* __restrict__ q,
                                                   const bf16* __restrict__ k,
                                                   const bf16* __restrict__ vt,
                                                   bf16* __restrict__ z) {
  __shared__ __align__(16) char smem[81920];
  const int tid = threadIdx.x, wave = tid >> 6, lane = tid & 63;
  const int lane15 = lane & 15, g = lane >> 4;
  const int qc = blockIdx.x, hh = blockIdx.y, bm = blockIdx.z;
  const int bh = bm * 8 + hh;
  const bf16* kbase = k + ((size_t)bh << 14);
  const bf16* vbase = vt + ((size_t)bh << 14);
  const bf16* qbase = q + ((size_t)bh << 14) + (qc * 64 + wave * 16) * 64;

#pragma unroll
  for (int i = 0; i < 8; ++i) {
    int s = i * 256 + tid;
    int kr = s >> 3, ksp = s & 7;                       // K: 8 slots/row
    gl_lds16(kbase + kr * 64 + (ksp ^ (kr & 7)) * 8, smem + s * 16);
    int ar = s >> 5, asp = s & 31;                      // Vt: 32 slots/row
    gl_lds16(vbase + ar * 256 + (asp ^ (ar & 7)) * 8, smem + 32768 + s * 16);
  }
  bf16v8 qf[2];
#pragma unroll
  for (int kk = 0; kk < 2; ++kk)
    qf[kk] = *(const bf16v8*)(qbase + lane15 * 64 + kk * 32 + g * 8);
  __syncthreads();

  // S = Q K^T : 16 col-tiles x 2 k-steps
  f32x4 sacc[16] = {};
#pragma unroll
  for (int tl = 0; tl < 16; ++tl) {
    int key = tl * 16 + lane15;
    int rb = key * 128, swk = (key & 7) << 4;
#pragma unroll
    for (int kk = 0; kk < 2; ++kk) {
      bf16v8 kf = *(const bf16v8*)(smem + rb + (((kk * 4 + g) * 16) ^ swk));
      sacc[tl] = __builtin_amdgcn_mfma_f32_16x16x32_bf16(qf[kk], kf, sacc[tl], 0, 0, 0);
    }
  }

  // softmax over 256 keys per q-row (rows live on (g, i); cols on lane15 x tile)
  float mx[4], sm[4], rcp[4];
#pragma unroll
  for (int i = 0; i < 4; ++i) mx[i] = sacc[0][i];
#pragma unroll
  for (int tl = 1; tl < 16; ++tl)
#pragma unroll
    for (int i = 0; i < 4; ++i) mx[i] = fmaxf(mx[i], sacc[tl][i]);
#pragma unroll
  for (int i = 0; i < 4; ++i) {
    mx[i] = fmaxf(mx[i], __shfl_xor(mx[i], 1));
    mx[i] = fmaxf(mx[i], __shfl_xor(mx[i], 2));
    mx[i] = fmaxf(mx[i], __shfl_xor(mx[i], 4));
    mx[i] = fmaxf(mx[i], __shfl_xor(mx[i], 8));
    sm[i] = 0.f;
  }
#pragma unroll
  for (int tl = 0; tl < 16; ++tl)
#pragma unroll
    for (int i = 0; i < 4; ++i) {
      float e = __expf((sacc[tl][i] - mx[i]) * 0.125f);
      sacc[tl][i] = e; sm[i] += e;
    }
#pragma unroll
  for (int i = 0; i < 4; ++i) {
    sm[i] += __shfl_xor(sm[i], 1);
    sm[i] += __shfl_xor(sm[i], 2);
    sm[i] += __shfl_xor(sm[i], 4);
    sm[i] += __shfl_xor(sm[i], 8);
    rcp[i] = 1.0f / sm[i];
  }

  // O = P V  (two key-halves through the per-wave P slab)
  char* pbase = smem + 65536 + wave * 4096;
  f32x4 oacc[4] = {};
#pragma unroll
  for (int h2 = 0; h2 < 2; ++h2) {
#pragma unroll
    for (int t8 = 0; t8 < 8; ++t8) {
      int tl = h2 * 8 + t8;
#pragma unroll
      for (int i = 0; i < 4; ++i) {
        int r = g * 4 + i;
        int c2 = t8 * 16 + lane15;
        *(bf16*)(pbase + r * 256 + ((c2 * 2) ^ ((r & 7) << 4))) =
            __float2bfloat16(sacc[tl][i] * rcp[i]);
      }
    }
    asm volatile("" ::: "memory");   // keep ds writes before dependent ds reads
#pragma unroll
    for (int k2 = 0; k2 < 4; ++k2) {
      int ks = h2 * 4 + k2;
      bf16v8 pf = *(const bf16v8*)(pbase + lane15 * 256 +
                                   ((k2 * 64 + g * 16) ^ ((lane15 & 7) << 4)));
#pragma unroll
      for (int at = 0; at < 4; ++at) {
        int a = at * 16 + lane15;
        bf16v8 vf = *(const bf16v8*)(smem + 32768 + a * 512 +
                                     ((ks * 64 + g * 16) ^ ((a & 7) << 4)));
        oacc[at] = __builtin_amdgcn_mfma_f32_16x16x32_bf16(pf, vf, oacc[at], 0, 0, 0);
      }
    }
    asm volatile("" ::: "memory");
  }

  int trow = bm * 256 + qc * 64 + wave * 16;
#pragma unroll
  for (int at = 0; at < 4; ++at)
#pragma unroll
    for (int i = 0; i < 4; ++i)
      z[(size_t)(trow + g * 4 + i) * 512 + hh * 64 + at * 16 + lane15] =
          __float2bfloat16(oacc[at][i]);
}

// ------------------------- layernorm kernels -------------------------
static __device__ __forceinline__ float wredsum(float v) {
  v += __shfl_xor(v, 1);  v += __shfl_xor(v, 2);  v += __shfl_xor(v, 4);
  v += __shfl_xor(v, 8);  v += __shfl_xor(v, 16); v += __shfl_xor(v, 32);
  return v;
}

// z2 = relu(x + LN(y1)*g1 + b1), one row per wave
__global__ __launch_bounds__(256) void ln_res_kernel(const bf16* __restrict__ y1,
                                                     const float* __restrict__ x,
                                                     const float* __restrict__ g1,
                                                     const float* __restrict__ b1,
                                                     bf16* __restrict__ z2) {
  const int wave = threadIdx.x >> 6, lane = threadIdx.x & 63;
  const int row = blockIdx.x * 4 + wave;
  const size_t base = (size_t)row * 512 + lane * 8;
  s16x8 yv = *(const s16x8*)(y1 + base);
  float f[8];
#pragma unroll
  for (int j = 0; j < 8; ++j) f[j] = bfu2f((unsigned short)yv[j]);
  float s = 0.f, s2 = 0.f;
#pragma unroll
  for (int j = 0; j < 8; ++j) { s += f[j]; s2 += f[j] * f[j]; }
  s = wredsum(s); s2 = wredsum(s2);
  float mu = s * (1.f / 512.f);
  float var = s2 * (1.f / 512.f) - mu * mu;
  float rs = rsqrtf(var + 1e-5f);
  float4 x0 = *(const float4*)(x + base);
  float4 x1 = *(const float4*)(x + base + 4);
  float xa[8] = {x0.x, x0.y, x0.z, x0.w, x1.x, x1.y, x1.z, x1.w};
  float ga[8], ba[8];
#pragma unroll
  for (int j = 0; j < 8; ++j) { ga[j] = g1[lane * 8 + j]; ba[j] = b1[lane * 8 + j]; }
  s16x8 ov;
#pragma unroll
  for (int j = 0; j < 8; ++j) {
    float v = xa[j] + (f[j] - mu) * rs * ga[j] + ba[j];
    ov[j] = (short)f2bfu(fmaxf(v, 0.f));
  }
  *(s16x8*)(z2 + base) = ov;
}

// out = relu(LN(y2)*g2 + b2), f32 in/out, one row per wave
__global__ __launch_bounds__(256) void ln_out_kernel(const float* __restrict__ y2,
                                                     const float* __restrict__ g2,
                                                     const float* __restrict__ b2,
                                                     float* __restrict__ out) {
  const int wave = threadIdx.x >> 6, lane = threadIdx.x & 63;
  const int row = blockIdx.x * 4 + wave;
  const size_t base = (size_t)row * 512 + lane * 8;
  float4 v0 = *(const float4*)(y2 + base);
  float4 v1 = *(const float4*)(y2 + base + 4);
  float f[8] = {v0.x, v0.y, v0.z, v0.w, v1.x, v1.y, v1.z, v1.w};
  float s = 0.f, s2 = 0.f;
#pragma unroll
  for (int j = 0; j < 8; ++j) { s += f[j]; s2 += f[j] * f[j]; }
  s = wredsum(s); s2 = wredsum(s2);
  float mu = s * (1.f / 512.f);
  float var = s2 * (1.f / 512.f) - mu * mu;
  float rs = rsqrtf(var + 1e-5f);
  float o[8];
#pragma unroll
  for (int j = 0; j < 8; ++j)
    o[j] = fmaxf((f[j] - mu) * rs * g2[lane * 8 + j] + b2[lane * 8 + j], 0.f);
  float4 w0 = {o[0], o[1], o[2], o[3]};
  float4 w1 = {o[4], o[5], o[6], o[7]};
  *(float4*)(out + base) = w0;
  *(float4*)(out + base + 4) = w1;
}

// ------------------------- launch -------------------------
extern "C" void kernel_launch(void* const* d_in, const int* in_sizes, int n_in,
                              void* d_out, int out_size, void* d_ws, size_t ws_size,
                              hipStream_t stream) {
  const float* x  = (const float*)d_in[0];
  const float* Wq = (const float*)d_in[1];
  const float* bq = (const float*)d_in[2];
  const float* Wk = (const float*)d_in[3];
  const float* bk = (const float*)d_in[4];
  const float* Wv = (const float*)d_in[5];
  const float* bv = (const float*)d_in[6];
  const float* Wo = (const float*)d_in[7];
  const float* bo = (const float*)d_in[8];
  const float* g1 = (const float*)d_in[9];
  const float* b1 = (const float*)d_in[10];
  const float* Wd = (const float*)d_in[11];
  const float* bd = (const float*)d_in[12];
  const float* g2 = (const float*)d_in[13];
  const float* b2 = (const float*)d_in[14];

  char* ws = (char*)d_ws;
  const size_t SEG = 50331648;
  bf16*  xb   = (bf16*)(ws);                       // x bf16 -> later z
  bf16*  qb   = (bf16*)(ws + SEG);                 // q      -> later y1
  bf16*  kb   = (bf16*)(ws + 2 * SEG);             // k      -> later z2
  bf16*  vtb  = (bf16*)(ws + 3 * SEG);             // v^T    -> later y2 (f32)
  bf16*  wqkv = (bf16*)(ws + 4 * SEG);
  bf16*  wot  = (bf16*)(ws + 4 * SEG + 1572864);
  bf16*  wdt  = (bf16*)(ws + 4 * SEG + 2097152);
  float* bqkv = (float*)(ws + 4 * SEG + 3145728);
  bf16*  zb   = xb;
  bf16*  y1   = qb;
  bf16*  z2   = kb;
  float* y2   = (float*)vtb;

  conv_x_kernel<<<4096, 256, 0, stream>>>((const float4*)x, (s16x4*)xb, 25165824 / 4);
  conv_w_kernel<<<6150, 256, 0, stream>>>(Wq, Wk, Wv, Wo, Wd, bq, bk, bv,
                                          wqkv, wot, wdt, bqkv);
  gemm128<0, 0><<<dim3(384, 12), 256, 0, stream>>>(xb, wqkv, bqkv, 512,
                                                   qb, kb, vtb, nullptr, nullptr);
  attn_kernel<<<dim3(4, 8, 192), 256, 0, stream>>>(qb, kb, vtb, zb);
  gemm128<1, 0><<<dim3(384, 4), 256, 0, stream>>>(zb, wot, bo, 512,
                                                  nullptr, nullptr, nullptr, y1, nullptr);
  ln_res_kernel<<<12288, 256, 0, stream>>>(y1, x, g1, b1, z2);
  gemm128<2, 1><<<dim3(192, 4), 256, 0, stream>>>(z2, wdt, bd, 1024,
                                                  nullptr, nullptr, nullptr, nullptr, y2);
  ln_out_kernel<<<6144, 256, 0, stream>>>(y2, g2, b2, (float*)d_out);
}

// Round 2
// 393.274 us; speedup vs baseline: 1.0370x; 1.0370x over previous
//
#include <hip/hip_runtime.h>
#include <hip/hip_bf16.h>
#include <stdint.h>

// VisionTransformerBlock on MI355X (gfx950).
// Pipeline: conv(x,W->bf16) -> QKV gemm -> attention -> Wo gemm -> LN1+res+relu
//           -> merged Wd gemm -> LN2+relu -> d_out (f32).
// GEMMs: 256x256 tile, BK=64, 8 waves, 8-phase counted-vmcnt schedule.

typedef __hip_bfloat16 bf16;
typedef __attribute__((ext_vector_type(8))) __bf16 bf16v8;
typedef __attribute__((ext_vector_type(4))) float f32x4;
typedef __attribute__((ext_vector_type(8))) short s16x8;
typedef __attribute__((ext_vector_type(4))) short s16x4;

static __device__ __forceinline__ void gl_lds16(const void* src, void* dst) {
  __builtin_amdgcn_global_load_lds((const __attribute__((address_space(1))) void*)src,
                                   (__attribute__((address_space(3))) void*)dst,
                                   16, 0, 0);
}

static __device__ __forceinline__ unsigned short f2bfu(float f) {
  return __builtin_bit_cast(unsigned short, __float2bfloat16(f));
}
static __device__ __forceinline__ float bfu2f(unsigned short u) {
  return __builtin_bit_cast(float, (unsigned int)u << 16);
}

// ------------------------- conversions -------------------------
__global__ __launch_bounds__(256) void conv_x_kernel(const float4* __restrict__ x,
                                                     s16x4* __restrict__ xb, int n4) {
  int stride = gridDim.x * 256;
  for (int i = blockIdx.x * 256 + threadIdx.x; i < n4; i += stride) {
    float4 v = x[i];
    s16x4 o;
    o[0] = (short)f2bfu(v.x); o[1] = (short)f2bfu(v.y);
    o[2] = (short)f2bfu(v.z); o[3] = (short)f2bfu(v.w);
    xb[i] = o;
  }
}

__global__ __launch_bounds__(256) void conv_w_kernel(
    const float* __restrict__ Wq, const float* __restrict__ Wk, const float* __restrict__ Wv,
    const float* __restrict__ Wo, const float* __restrict__ Wd,
    const float* __restrict__ bq, const float* __restrict__ bk, const float* __restrict__ bv,
    bf16* __restrict__ wqkv_t, bf16* __restrict__ wo_t, bf16* __restrict__ wd_t,
    float* __restrict__ bqkv) {
  int o = blockIdx.x * 256 + threadIdx.x;
  if (o < 786432) {                       // wqkv_t[j][kk], j in [0,1536)
    int j = o >> 9, kk = o & 511;
    const float* W = (j < 512) ? Wq : (j < 1024) ? Wk : Wv;
    wqkv_t[o] = __float2bfloat16(W[kk * 512 + (j & 511)]);
  } else if (o < 1048576) {               // wo_t[j][kk]
    int o2 = o - 786432; int j = o2 >> 9, kk = o2 & 511;
    wo_t[o2] = __float2bfloat16(Wo[kk * 512 + j]);
  } else if (o < 1572864) {               // wd_t[j][kk], kk in [0,1024)
    int o3 = o - 1048576; int j = o3 >> 10, kk = o3 & 1023;
    wd_t[o3] = __float2bfloat16(Wd[kk * 512 + j]);
  } else if (o < 1574400) {               // bqkv concat (f32)
    int o4 = o - 1572864;
    const float* b = (o4 < 512) ? bq : (o4 < 1024) ? bk : bv;
    bqkv[o4] = b[o4 & 511];
  }
}

// ------------------------- GEMM 256x256, BK=64, 8-phase -------------------------
// A: bf16 row-major [M][K] (AMODE1: patch-merged view of z2 [49152][512]).
// Bt: bf16 [N][K]. LDS: 2 buffers x (A[256][64] + B[256][64]) = 128 KB.
// Row layout: 8 x 16B slots, physical slot = logical_chunk ^ (row&7)
// (inverse swizzle applied on the global source; global_load_lds dest linear).
// Per iteration: 2 K-tiles (t0=2i buf0 phases 0-3, t1 buf1 phases 4-7).
// Phase p=(mh,nh) computes quadrant (mh*64 rows, nh*32 cols) of the wave tile
// over full BK=64 (16 MFMA). Staging schedule (half-tile per phase):
//   p0:A(t1)h1  p1:B(t1)h0  p2:B(t1)h1  p3:A(t0+2)h0  p4:A(t0+2)h1
//   p5:B(t0+2)h0  p6:B(t0+2)h1  p7:A(t1+2)h0
// Each region is staged >=1 barrier after its last read completes (lgkm0 before
// closing barrier). vmcnt(2) before the closing barrier of p3 and p7 guarantees
// everything except the newest half-tile has landed before its first read.
// EPI 0: qkv scatter; 1: bf16 row-major out; 2: f32 row-major out. ldc=512.
template<int EPI, int AMODE>
__global__ __launch_bounds__(512, 2) void gemm256(
    const bf16* __restrict__ A, const bf16* __restrict__ Bt,
    const float* __restrict__ bias, int K,
    bf16* __restrict__ oq, bf16* __restrict__ ok, bf16* __restrict__ ovt,
    bf16* __restrict__ obf, float* __restrict__ of) {
  __shared__ __align__(16) char smem[131072];
  const int tid = threadIdx.x;
  const int wave = tid >> 6, lane = tid & 63;
  const int wr = wave >> 2, wc = wave & 3;         // 2M x 4N waves
  const int lane15 = lane & 15, g = lane >> 4;
  const int tileM = blockIdx.x * 256, tileN = blockIdx.y * 256;

  // staging per-thread constants: 1024 16B-slots per half-tile, 2 per thread
  const int rT = tid >> 3;                 // row within half (j=0), +64 for j=1
  const int cT = (tid & 7) ^ (rT & 7);     // inverse-swizzled logical chunk

  const int nkt = K >> 6;
  const int iters = nkt >> 1;

  auto stage = [&](int idx) {
    int tau = idx >> 2, q = idx & 3;       // q: 0 A.h0, 1 A.h1, 2 B.h0, 3 B.h1
    char* dst = smem + ((tau & 1) << 16) + ((q >> 1) << 15) + ((q & 1) << 14) + tid * 16;
    int kpos = tau * 64 + cT * 8;
    if (q < 2) {
      int rowA = tileM + ((q & 1) << 7) + rT;
      if (AMODE == 0) {
        const bf16* s0 = A + (size_t)rowA * K + kpos;
        gl_lds16(s0, dst);
        gl_lds16(s0 + (size_t)64 * K, dst + 8192);
      } else {
#pragma unroll
        for (int j = 0; j < 2; ++j) {
          int mr = rowA + j * 64;
          int bm = mr >> 7, pp = mr & 127;
          const bf16* s = A + (size_t)(bm * 256 + pp * 2 + (kpos >> 9)) * 512 + (kpos & 511);
          gl_lds16(s, dst + j * 8192);
        }
      }
    } else {
      int rowB = tileN + ((q & 1) << 7) + rT;
      const bf16* s0 = Bt + (size_t)rowB * K + kpos;
      gl_lds16(s0, dst);
      gl_lds16(s0 + (size_t)64 * K, dst + 8192);
    }
  };

  f32x4 acc[8][4] = {};
  bf16v8 areg[4][2], breg[2][2];

  // prologue: tile 0 (4 half-tiles) + A(1)h0
  for (int idx = 0; idx < 5; ++idx) stage(idx);
  asm volatile("s_waitcnt vmcnt(2)" ::: "memory");
  __builtin_amdgcn_s_barrier();

  for (int it = 0; it < iters; ++it) {
    const bool last = (it == iters - 1);
#pragma unroll
    for (int p = 0; p < 8; ++p) {
      const int buf = p >> 2;              // tile (2*it + buf)
      const int mh = (p >> 1) & 1, nh = p & 1;
      char* Ab = smem + (buf << 16);
      char* Bb = Ab + 32768;
      // ds-read register subtile
      if (nh == 0) {
#pragma unroll
        for (int f = 0; f < 4; ++f) {
          int row = wr * 128 + (mh * 4 + f) * 16 + lane15;
#pragma unroll
          for (int ks = 0; ks < 2; ++ks)
            areg[f][ks] = *(const bf16v8*)(Ab + row * 128 + (((ks * 4 + g) ^ (row & 7)) << 4));
        }
      }
#pragma unroll
      for (int n = 0; n < 2; ++n) {
        int row = wc * 64 + (nh * 2 + n) * 16 + lane15;
#pragma unroll
        for (int ks = 0; ks < 2; ++ks)
          breg[n][ks] = *(const bf16v8*)(Bb + row * 128 + (((ks * 4 + g) ^ (row & 7)) << 4));
      }
      // stage one half-tile (skips only in the last iteration, p>=3)
      if (!last || p < 3) stage(it * 8 + p + 5);
      __builtin_amdgcn_s_barrier();
      asm volatile("s_waitcnt lgkmcnt(0)" ::: "memory");
      __builtin_amdgcn_s_setprio(1);
#pragma unroll
      for (int ks = 0; ks < 2; ++ks)
#pragma unroll
        for (int f = 0; f < 4; ++f)
#pragma unroll
          for (int n = 0; n < 2; ++n)
            acc[mh * 4 + f][nh * 2 + n] = __builtin_amdgcn_mfma_f32_16x16x32_bf16(
                areg[f][ks], breg[n][ks], acc[mh * 4 + f][nh * 2 + n], 0, 0, 0);
      __builtin_amdgcn_s_setprio(0);
      if (p == 3) {
        if (last) { asm volatile("s_waitcnt vmcnt(0)" ::: "memory"); }
        else      { asm volatile("s_waitcnt vmcnt(2)" ::: "memory"); }
      } else if (p == 7) {
        asm volatile("s_waitcnt vmcnt(2)" ::: "memory");
      }
      __builtin_amdgcn_s_barrier();
    }
  }

  // epilogue
#pragma unroll
  for (int fm = 0; fm < 8; ++fm) {
#pragma unroll
    for (int fn = 0; fn < 4; ++fn) {
      int col = tileN + wc * 64 + fn * 16 + lane15;
      float bb = bias[col];
#pragma unroll
      for (int i = 0; i < 4; ++i) {
        int row = tileM + wr * 128 + fm * 16 + g * 4 + i;
        float val = acc[fm][fn][i] + bb;
        if (EPI == 0) {
          int bm = row >> 8, p = row & 255;
          if (col < 512) {
            int hh = col >> 6, a = col & 63;
            oq[((size_t)(bm * 8 + hh) << 14) + (p << 6) + a] = __float2bfloat16(val);
          } else if (col < 1024) {
            int j = col - 512; int hh = j >> 6, a = j & 63;
            ok[((size_t)(bm * 8 + hh) << 14) + (p << 6) + a] = __float2bfloat16(val);
          } else {
            int j = col - 1024; int hh = j >> 6, a = j & 63;
            ovt[((size_t)(bm * 8 + hh) << 14) + (a << 8) + p] = __float2bfloat16(val);
          }
        } else if (EPI == 1) {
          obf[(size_t)row * 512 + col] = __float2bfloat16(val);
        } else {
          of[(size_t)row * 512 + col] = val;
        }
      }
    }
  }
}

// ------------------------- attention -------------------------
// Block = (qc, h, bm): 64 q-rows, 4 waves x 16 rows. LDS: K[256][64] (swz),
// Vt[64][256] (swz), P per-wave 16x128 bf16 round-trip slab (swz). 80 KB.
__global__ __launch_bounds__(256) void attn_kernel(const bf16* __restrict__ q,
                                                   const bf16* __restrict__ k,
                                                   const bf16* __restrict__ vt,
                                                   bf16* __restrict__ z) {
  __shared__ __align__(16) char smem[81920];
  const int tid = threadIdx.x, wave = tid >> 6, lane = tid & 63;
  const int lane15 = lane & 15, g = lane >> 4;
  const int qc = blockIdx.x, hh = blockIdx.y, bm = blockIdx.z;
  const int bh = bm * 8 + hh;
  const bf16* kbase = k + ((size_t)bh << 14);
  const bf16* vbase = vt + ((size_t)bh << 14);
  const bf16* qbase = q + ((size_t)bh << 14) + (qc * 64 + wave * 16) * 64;

#pragma unroll
  for (int i = 0; i < 8; ++i) {
    int s = i * 256 + tid;
    int kr = s >> 3, ksp = s & 7;                       // K: 8 slots/row
    gl_lds16(kbase + kr * 64 + (ksp ^ (kr & 7)) * 8, smem + s * 16);
    int ar = s >> 5, asp = s & 31;                      // Vt: 32 slots/row
    gl_lds16(vbase + ar * 256 + (asp ^ (ar & 7)) * 8, smem + 32768 + s * 16);
  }
  bf16v8 qf[2];
#pragma unroll
  for (int kk = 0; kk < 2; ++kk)
    qf[kk] = *(const bf16v8*)(qbase + lane15 * 64 + kk * 32 + g * 8);
  __syncthreads();

  // S = Q K^T : 16 col-tiles x 2 k-steps
  f32x4 sacc[16] = {};
#pragma unroll
  for (int tl = 0; tl < 16; ++tl) {
    int key = tl * 16 + lane15;
    int rb = key * 128, swk = (key & 7) << 4;
#pragma unroll
    for (int kk = 0; kk < 2; ++kk) {
      bf16v8 kf = *(const bf16v8*)(smem + rb + (((kk * 4 + g) * 16) ^ swk));
      sacc[tl] = __builtin_amdgcn_mfma_f32_16x16x32_bf16(qf[kk], kf, sacc[tl], 0, 0, 0);
    }
  }

  // softmax over 256 keys per q-row (rows live on (g, i); cols on lane15 x tile)
  float mx[4], sm[4], rcp[4];
#pragma unroll
  for (int i = 0; i < 4; ++i) mx[i] = sacc[0][i];
#pragma unroll
  for (int tl = 1; tl < 16; ++tl)
#pragma unroll
    for (int i = 0; i < 4; ++i) mx[i] = fmaxf(mx[i], sacc[tl][i]);
#pragma unroll
  for (int i = 0; i < 4; ++i) {
    mx[i] = fmaxf(mx[i], __shfl_xor(mx[i], 1));
    mx[i] = fmaxf(mx[i], __shfl_xor(mx[i], 2));
    mx[i] = fmaxf(mx[i], __shfl_xor(mx[i], 4));
    mx[i] = fmaxf(mx[i], __shfl_xor(mx[i], 8));
    sm[i] = 0.f;
  }
#pragma unroll
  for (int tl = 0; tl < 16; ++tl)
#pragma unroll
    for (int i = 0; i < 4; ++i) {
      float e = __expf((sacc[tl][i] - mx[i]) * 0.125f);
      sacc[tl][i] = e; sm[i] += e;
    }
#pragma unroll
  for (int i = 0; i < 4; ++i) {
    sm[i] += __shfl_xor(sm[i], 1);
    sm[i] += __shfl_xor(sm[i], 2);
    sm[i] += __shfl_xor(sm[i], 4);
    sm[i] += __shfl_xor(sm[i], 8);
    rcp[i] = 1.0f / sm[i];
  }

  // O = P V  (two key-halves through the per-wave P slab)
  char* pbase = smem + 65536 + wave * 4096;
  f32x4 oacc[4] = {};
#pragma unroll
  for (int h2 = 0; h2 < 2; ++h2) {
#pragma unroll
    for (int t8 = 0; t8 < 8; ++t8) {
      int tl = h2 * 8 + t8;
#pragma unroll
      for (int i = 0; i < 4; ++i) {
        int r = g * 4 + i;
        int c2 = t8 * 16 + lane15;
        *(bf16*)(pbase + r * 256 + ((c2 * 2) ^ ((r & 7) << 4))) =
            __float2bfloat16(sacc[tl][i] * rcp[i]);
      }
    }
    asm volatile("" ::: "memory");   // keep ds writes before dependent ds reads
#pragma unroll
    for (int k2 = 0; k2 < 4; ++k2) {
      int ks = h2 * 4 + k2;
      bf16v8 pf = *(const bf16v8*)(pbase + lane15 * 256 +
                                   ((k2 * 64 + g * 16) ^ ((lane15 & 7) << 4)));
#pragma unroll
      for (int at = 0; at < 4; ++at) {
        int a = at * 16 + lane15;
        bf16v8 vf = *(const bf16v8*)(smem + 32768 + a * 512 +
                                     ((ks * 64 + g * 16) ^ ((a & 7) << 4)));
        oacc[at] = __builtin_amdgcn_mfma_f32_16x16x32_bf16(pf, vf, oacc[at], 0, 0, 0);
      }
    }
    asm volatile("" ::: "memory");
  }

  int trow = bm * 256 + qc * 64 + wave * 16;
#pragma unroll
  for (int at = 0; at < 4; ++at)
#pragma unroll
    for (int i = 0; i < 4; ++i)
      z[(size_t)(trow + g * 4 + i) * 512 + hh * 64 + at * 16 + lane15] =
          __float2bfloat16(oacc[at][i]);
}

// ------------------------- layernorm kernels -------------------------
static __device__ __forceinline__ float wredsum(float v) {
  v += __shfl_xor(v, 1);  v += __shfl_xor(v, 2);  v += __shfl_xor(v, 4);
  v += __shfl_xor(v, 8);  v += __shfl_xor(v, 16); v += __shfl_xor(v, 32);
  return v;
}

// z2 = relu(x + LN(y1)*g1 + b1), one row per wave
__global__ __launch_bounds__(256) void ln_res_kernel(const bf16* __restrict__ y1,
                                                     const float* __restrict__ x,
                                                     const float* __restrict__ g1,
                                                     const float* __restrict__ b1,
                                                     bf16* __restrict__ z2) {
  const int wave = threadIdx.x >> 6, lane = threadIdx.x & 63;
  const int row = blockIdx.x * 4 + wave;
  const size_t base = (size_t)row * 512 + lane * 8;
  s16x8 yv = *(const s16x8*)(y1 + base);
  float f[8];
#pragma unroll
  for (int j = 0; j < 8; ++j) f[j] = bfu2f((unsigned short)yv[j]);
  float s = 0.f, s2 = 0.f;
#pragma unroll
  for (int j = 0; j < 8; ++j) { s += f[j]; s2 += f[j] * f[j]; }
  s = wredsum(s); s2 = wredsum(s2);
  float mu = s * (1.f / 512.f);
  float var = s2 * (1.f / 512.f) - mu * mu;
  float rs = rsqrtf(var + 1e-5f);
  float4 x0 = *(const float4*)(x + base);
  float4 x1 = *(const float4*)(x + base + 4);
  float xa[8] = {x0.x, x0.y, x0.z, x0.w, x1.x, x1.y, x1.z, x1.w};
  float ga[8], ba[8];
#pragma unroll
  for (int j = 0; j < 8; ++j) { ga[j] = g1[lane * 8 + j]; ba[j] = b1[lane * 8 + j]; }
  s16x8 ov;
#pragma unroll
  for (int j = 0; j < 8; ++j) {
    float v = xa[j] + (f[j] - mu) * rs * ga[j] + ba[j];
    ov[j] = (short)f2bfu(fmaxf(v, 0.f));
  }
  *(s16x8*)(z2 + base) = ov;
}

// out = relu(LN(y2)*g2 + b2), f32 in/out, one row per wave
__global__ __launch_bounds__(256) void ln_out_kernel(const float* __restrict__ y2,
                                                     const float* __restrict__ g2,
                                                     const float* __restrict__ b2,
                                                     float* __restrict__ out) {
  const int wave = threadIdx.x >> 6, lane = threadIdx.x & 63;
  const int row = blockIdx.x * 4 + wave;
  const size_t base = (size_t)row * 512 + lane * 8;
  float4 v0 = *(const float4*)(y2 + base);
  float4 v1 = *(const float4*)(y2 + base + 4);
  float f[8] = {v0.x, v0.y, v0.z, v0.w, v1.x, v1.y, v1.z, v1.w};
  float s = 0.f, s2 = 0.f;
#pragma unroll
  for (int j = 0; j < 8; ++j) { s += f[j]; s2 += f[j] * f[j]; }
  s = wredsum(s); s2 = wredsum(s2);
  float mu = s * (1.f / 512.f);
  float var = s2 * (1.f / 512.f) - mu * mu;
  float rs = rsqrtf(var + 1e-5f);
  float o[8];
#pragma unroll
  for (int j = 0; j < 8; ++j)
    o[j] = fmaxf((f[j] - mu) * rs * g2[lane * 8 + j] + b2[lane * 8 + j], 0.f);
  float4 w0 = {o[0], o[1], o[2], o[3]};
  float4 w1 = {o[4], o[5], o[6], o[7]};
  *(float4*)(out + base) = w0;
  *(float4*)(out + base + 4) = w1;
}

// ------------------------- launch -------------------------
extern "C" void kernel_launch(void* const* d_in, const int* in_sizes, int n_in,
                              void* d_out, int out_size, void* d_ws, size_t ws_size,
                              hipStream_t stream) {
  const float* x  = (const float*)d_in[0];
  const float* Wq = (const float*)d_in[1];
  const float* bq = (const float*)d_in[2];
  const float* Wk = (const float*)d_in[3];
  const float* bk = (const float*)d_in[4];
  const float* Wv = (const float*)d_in[5];
  const float* bv = (const float*)d_in[6];
  const float* Wo = (const float*)d_in[7];
  const float* bo = (const float*)d_in[8];
  const float* g1 = (const float*)d_in[9];
  const float* b1 = (const float*)d_in[10];
  const float* Wd = (const float*)d_in[11];
  const float* bd = (const float*)d_in[12];
  const float* g2 = (const float*)d_in[13];
  const float* b2 = (const float*)d_in[14];

  char* ws = (char*)d_ws;
  const size_t SEG = 50331648;
  bf16*  xb   = (bf16*)(ws);                       // x bf16 -> later z
  bf16*  qb   = (bf16*)(ws + SEG);                 // q      -> later y1
  bf16*  kb   = (bf16*)(ws + 2 * SEG);             // k      -> later z2
  bf16*  vtb  = (bf16*)(ws + 3 * SEG);             // v^T    -> later y2 (f32)
  bf16*  wqkv = (bf16*)(ws + 4 * SEG);
  bf16*  wot  = (bf16*)(ws + 4 * SEG + 1572864);
  bf16*  wdt  = (bf16*)(ws + 4 * SEG + 2097152);
  float* bqkv = (float*)(ws + 4 * SEG + 3145728);
  bf16*  zb   = xb;
  bf16*  y1   = qb;
  bf16*  z2   = kb;
  float* y2   = (float*)vtb;

  conv_x_kernel<<<4096, 256, 0, stream>>>((const float4*)x, (s16x4*)xb, 25165824 / 4);
  conv_w_kernel<<<6150, 256, 0, stream>>>(Wq, Wk, Wv, Wo, Wd, bq, bk, bv,
                                          wqkv, wot, wdt, bqkv);
  gemm256<0, 0><<<dim3(192, 6), 512, 0, stream>>>(xb, wqkv, bqkv, 512,
                                                  qb, kb, vtb, nullptr, nullptr);
  attn_kernel<<<dim3(4, 8, 192), 256, 0, stream>>>(qb, kb, vtb, zb);
  gemm256<1, 0><<<dim3(192, 2), 512, 0, stream>>>(zb, wot, bo, 512,
                                                  nullptr, nullptr, nullptr, y1, nullptr);
  ln_res_kernel<<<12288, 256, 0, stream>>>(y1, x, g1, b1, z2);
  gemm256<2, 1><<<dim3(96, 2), 512, 0, stream>>>(z2, wdt, bd, 1024,
                                                 nullptr, nullptr, nullptr, nullptr, y2);
  ln_out_kernel<<<6144, 256, 0, stream>>>(y2, g2, b2, (float*)d_out);
}

// Round 3
// 348.759 us; speedup vs baseline: 1.1694x; 1.1276x over previous
//
#include <hip/hip_runtime.h>
#include <hip/hip_bf16.h>
#include <stdint.h>

// VisionTransformerBlock on MI355X (gfx950).
// Pipeline: conv(x,W->bf16) -> QKV gemm -> attention -> Wo gemm -> LN1+res+relu
//           -> merged Wd gemm -> LN2+relu -> d_out (f32).
// GEMMs: 256x256 tile, BK=64, 8 waves, 8-phase schedule with max-slack staging:
//   p0: B(2i+1) both halves | p3: A(2i+2) | p4: B(2i+2) | p7: A(2i+3)
//   vmcnt(4) at p3close and p7close (only the current phase's 4 ops in flight).
// v^T epilogue: per-wave LDS transpose -> 256B-coalesced b128 stores.

typedef __hip_bfloat16 bf16;
typedef __attribute__((ext_vector_type(8))) __bf16 bf16v8;
typedef __attribute__((ext_vector_type(4))) float f32x4;
typedef __attribute__((ext_vector_type(8))) short s16x8;
typedef __attribute__((ext_vector_type(4))) short s16x4;

static __device__ __forceinline__ void gl_lds16(const void* src, void* dst) {
  __builtin_amdgcn_global_load_lds((const __attribute__((address_space(1))) void*)src,
                                   (__attribute__((address_space(3))) void*)dst,
                                   16, 0, 0);
}

static __device__ __forceinline__ unsigned short f2bfu(float f) {
  return __builtin_bit_cast(unsigned short, __float2bfloat16(f));
}
static __device__ __forceinline__ float bfu2f(unsigned short u) {
  return __builtin_bit_cast(float, (unsigned int)u << 16);
}

// ------------------------- conversions -------------------------
__global__ __launch_bounds__(256) void conv_x_kernel(const float4* __restrict__ x,
                                                     s16x4* __restrict__ xb, int n4) {
  int stride = gridDim.x * 256;
  for (int i = blockIdx.x * 256 + threadIdx.x; i < n4; i += stride) {
    float4 v = x[i];
    s16x4 o;
    o[0] = (short)f2bfu(v.x); o[1] = (short)f2bfu(v.y);
    o[2] = (short)f2bfu(v.z); o[3] = (short)f2bfu(v.w);
    xb[i] = o;
  }
}

__global__ __launch_bounds__(256) void conv_w_kernel(
    const float* __restrict__ Wq, const float* __restrict__ Wk, const float* __restrict__ Wv,
    const float* __restrict__ Wo, const float* __restrict__ Wd,
    const float* __restrict__ bq, const float* __restrict__ bk, const float* __restrict__ bv,
    bf16* __restrict__ wqkv_t, bf16* __restrict__ wo_t, bf16* __restrict__ wd_t,
    float* __restrict__ bqkv) {
  int o = blockIdx.x * 256 + threadIdx.x;
  if (o < 786432) {                       // wqkv_t[j][kk], j in [0,1536)
    int j = o >> 9, kk = o & 511;
    const float* W = (j < 512) ? Wq : (j < 1024) ? Wk : Wv;
    wqkv_t[o] = __float2bfloat16(W[kk * 512 + (j & 511)]);
  } else if (o < 1048576) {               // wo_t[j][kk]
    int o2 = o - 786432; int j = o2 >> 9, kk = o2 & 511;
    wo_t[o2] = __float2bfloat16(Wo[kk * 512 + j]);
  } else if (o < 1572864) {               // wd_t[j][kk], kk in [0,1024)
    int o3 = o - 1048576; int j = o3 >> 10, kk = o3 & 1023;
    wd_t[o3] = __float2bfloat16(Wd[kk * 512 + j]);
  } else if (o < 1574400) {               // bqkv concat (f32)
    int o4 = o - 1572864;
    const float* b = (o4 < 512) ? bq : (o4 < 1024) ? bk : bv;
    bqkv[o4] = b[o4 & 511];
  }
}

// ------------------------- GEMM 256x256, BK=64, 8-phase -------------------------
// A: bf16 row-major [M][K] (AMODE1: patch-merged view of z2 [49152][512]).
// Bt: bf16 [N][K]. LDS: 2 buffers x (A[256][64] + B[256][64]) = 128 KB.
// Row layout: 8 x 16B slots, physical slot = logical_chunk ^ (row&7)
// (inverse swizzle applied on the global source; global_load_lds dest linear).
// Region-free ledger (iteration i computes tile 2i in buf0 at p0-3, 2i+1 in
// buf1 at p4-7; A halves read only at nh==0 phases, B at every phase):
//   buf0.A free after p2close -> stage A(2i+2) at p3
//   buf0.B free after p3close -> stage B(2i+2) at p4
//   buf1.A free after p6close -> stage A(2i+3) at p7
//   buf1.B free after p7close -> stage B(2i+1) at p0 (of the SAME iteration)
// Deadlines: tile 2i+1 complete by p3close (vmcnt(4)); tile 2i+2 by p7close
// (vmcnt(4)). Min slack = 3 phases. Never vmcnt(0) mid-loop.
// EPI 0: qkv scatter (v via LDS transpose); 1: bf16 out; 2: f32 out. ldc=512.
template<int EPI, int AMODE>
__global__ __launch_bounds__(512, 2) void gemm256(
    const bf16* __restrict__ A, const bf16* __restrict__ Bt,
    const float* __restrict__ bias, int K,
    bf16* __restrict__ oq, bf16* __restrict__ ok, bf16* __restrict__ ovt,
    bf16* __restrict__ obf, float* __restrict__ of) {
  __shared__ __align__(16) char smem[131072];
  const int tid = threadIdx.x;
  const int wave = tid >> 6, lane = tid & 63;
  const int wr = wave >> 2, wc = wave & 3;         // 2M x 4N waves
  const int lane15 = lane & 15, g = lane >> 4;
  const int tileM = blockIdx.x * 256, tileN = blockIdx.y * 256;

  // staging per-thread constants: 1024 16B-slots per half-tile, 2 per thread
  const int rT = tid >> 3;                 // row within half (j=0), +64 for j=1
  const int cT = (tid & 7) ^ (rT & 7);     // inverse-swizzled logical chunk

  const int nkt = K >> 6;
  const int iters = nkt >> 1;

  // stage one half-tile: tau = K-tile index, q: 0 A.h0, 1 A.h1, 2 B.h0, 3 B.h1
  auto stage = [&](int tau, int q) {
    char* dst = smem + ((tau & 1) << 16) + ((q >> 1) << 15) + ((q & 1) << 14) + tid * 16;
    int kpos = tau * 64 + cT * 8;
    if (q < 2) {
      int rowA = tileM + ((q & 1) << 7) + rT;
      if (AMODE == 0) {
        const bf16* s0 = A + (size_t)rowA * K + kpos;
        gl_lds16(s0, dst);
        gl_lds16(s0 + (size_t)64 * K, dst + 8192);
      } else {
#pragma unroll
        for (int j = 0; j < 2; ++j) {
          int mr = rowA + j * 64;
          int bm = mr >> 7, pp = mr & 127;
          const bf16* s = A + (size_t)(bm * 256 + pp * 2 + (kpos >> 9)) * 512 + (kpos & 511);
          gl_lds16(s, dst + j * 8192);
        }
      }
    } else {
      int rowB = tileN + ((q & 1) << 7) + rT;
      const bf16* s0 = Bt + (size_t)rowB * K + kpos;
      gl_lds16(s0, dst);
      gl_lds16(s0 + (size_t)64 * K, dst + 8192);
    }
  };

  f32x4 acc[8][4] = {};
  bf16v8 areg[4][2], breg[2][2];

  // prologue: tile 0 fully + A(1) halves   (12 vmcnt units)
  stage(0, 0); stage(0, 1); stage(0, 2); stage(0, 3);
  stage(1, 0); stage(1, 1);
  asm volatile("s_waitcnt vmcnt(4)" ::: "memory");   // tile 0 landed
  __builtin_amdgcn_s_barrier();

  for (int it = 0; it < iters; ++it) {
    const bool last = (it == iters - 1);
#pragma unroll
    for (int p = 0; p < 8; ++p) {
      const int buf = p >> 2;              // tile (2*it + buf)
      const int mh = (p >> 1) & 1, nh = p & 1;
      char* Ab = smem + (buf << 16);
      char* Bb = Ab + 32768;
      // ds-read register subtile
      if (nh == 0) {
#pragma unroll
        for (int f = 0; f < 4; ++f) {
          int row = wr * 128 + (mh * 4 + f) * 16 + lane15;
#pragma unroll
          for (int ks = 0; ks < 2; ++ks)
            areg[f][ks] = *(const bf16v8*)(Ab + row * 128 + (((ks * 4 + g) ^ (row & 7)) << 4));
        }
      }
#pragma unroll
      for (int n = 0; n < 2; ++n) {
        int row = wc * 64 + (nh * 2 + n) * 16 + lane15;
#pragma unroll
        for (int ks = 0; ks < 2; ++ks)
          breg[n][ks] = *(const bf16v8*)(Bb + row * 128 + (((ks * 4 + g) ^ (row & 7)) << 4));
      }
      // max-slack staging (region freed by the previous closing barrier)
      if (p == 0)      { stage(2 * it + 1, 2); stage(2 * it + 1, 3); }
      else if (p == 3) { if (!last) { stage(2 * it + 2, 0); stage(2 * it + 2, 1); } }
      else if (p == 4) { if (!last) { stage(2 * it + 2, 2); stage(2 * it + 2, 3); } }
      else if (p == 7) { if (!last) { stage(2 * it + 3, 0); stage(2 * it + 3, 1); } }
      __builtin_amdgcn_s_barrier();
      asm volatile("s_waitcnt lgkmcnt(0)" ::: "memory");
      __builtin_amdgcn_s_setprio(1);
#pragma unroll
      for (int ks = 0; ks < 2; ++ks)
#pragma unroll
        for (int f = 0; f < 4; ++f)
#pragma unroll
          for (int n = 0; n < 2; ++n)
            acc[mh * 4 + f][nh * 2 + n] = __builtin_amdgcn_mfma_f32_16x16x32_bf16(
                areg[f][ks], breg[n][ks], acc[mh * 4 + f][nh * 2 + n], 0, 0, 0);
      __builtin_amdgcn_s_setprio(0);
      if (p == 3) {
        if (last) { asm volatile("s_waitcnt vmcnt(0)" ::: "memory"); }
        else      { asm volatile("s_waitcnt vmcnt(4)" ::: "memory"); }
      } else if (p == 7) {
        if (!last) { asm volatile("s_waitcnt vmcnt(4)" ::: "memory"); }
      }
      __builtin_amdgcn_s_barrier();
    }
  }

  // ------------------------- epilogue -------------------------
  if (EPI == 0 && tileN >= 1024) {
    // v-block: bias + bf16 into per-wave LDS slab [64 a][128 p] (swizzled),
    // then 16 coalesced b128 stores per wave into vt[bh][a][p].
    const int hh = ((tileN - 1024) >> 6) + wc;
    const int bm = tileM >> 8;
    char* slab = smem + wave * 16384;
#pragma unroll
    for (int fm = 0; fm < 8; ++fm) {
#pragma unroll
      for (int fn = 0; fn < 4; ++fn) {
        int col = tileN + wc * 64 + fn * 16 + lane15;
        float bb = bias[col];
        int a = fn * 16 + lane15;
#pragma unroll
        for (int i = 0; i < 4; ++i) {
          int pl = fm * 16 + g * 4 + i;
          *(bf16*)(slab + a * 256 + ((pl * 2) ^ ((a & 7) << 4))) =
              __float2bfloat16(acc[fm][fn][i] + bb);
        }
      }
    }
    bf16* vdst = ovt + ((size_t)(bm * 8 + hh) << 14) + wr * 128;
#pragma unroll
    for (int r = 0; r < 16; ++r) {
      int a = r * 4 + (lane >> 4);
      int ps = lane & 15;
      s16x8 vv = *(const s16x8*)(slab + a * 256 + ((ps * 16) ^ ((a & 7) << 4)));
      *(s16x8*)(vdst + a * 256 + ps * 8) = vv;
    }
  } else {
#pragma unroll
    for (int fm = 0; fm < 8; ++fm) {
#pragma unroll
      for (int fn = 0; fn < 4; ++fn) {
        int col = tileN + wc * 64 + fn * 16 + lane15;
        float bb = bias[col];
#pragma unroll
        for (int i = 0; i < 4; ++i) {
          int row = tileM + wr * 128 + fm * 16 + g * 4 + i;
          float val = acc[fm][fn][i] + bb;
          if (EPI == 0) {
            int bm = row >> 8, p = row & 255;
            int hh = col >> 6, a = col & 63;
            if (col < 512) {
              oq[((size_t)(bm * 8 + hh) << 14) + (p << 6) + a] = __float2bfloat16(val);
            } else {
              int j = col - 512; hh = j >> 6; a = j & 63;
              ok[((size_t)(bm * 8 + hh) << 14) + (p << 6) + a] = __float2bfloat16(val);
            }
          } else if (EPI == 1) {
            obf[(size_t)row * 512 + col] = __float2bfloat16(val);
          } else {
            of[(size_t)row * 512 + col] = val;
          }
        }
      }
    }
  }
}

// ------------------------- attention -------------------------
// Block = (qc, h, bm): 64 q-rows, 4 waves x 16 rows. LDS: K[256][64] (swz),
// Vt[64][256] (swz), P per-wave 16x128 bf16 round-trip slab (swz). 80 KB.
__global__ __launch_bounds__(256) void attn_kernel(const bf16* __restrict__ q,
                                                   const bf16* __restrict__ k,
                                                   const bf16* __restrict__ vt,
                                                   bf16* __restrict__ z) {
  __shared__ __align__(16) char smem[81920];
  const int tid = threadIdx.x, wave = tid >> 6, lane = tid & 63;
  const int lane15 = lane & 15, g = lane >> 4;
  const int qc = blockIdx.x, hh = blockIdx.y, bm = blockIdx.z;
  const int bh = bm * 8 + hh;
  const bf16* kbase = k + ((size_t)bh << 14);
  const bf16* vbase = vt + ((size_t)bh << 14);
  const bf16* qbase = q + ((size_t)bh << 14) + (qc * 64 + wave * 16) * 64;

#pragma unroll
  for (int i = 0; i < 8; ++i) {
    int s = i * 256 + tid;
    int kr = s >> 3, ksp = s & 7;                       // K: 8 slots/row
    gl_lds16(kbase + kr * 64 + (ksp ^ (kr & 7)) * 8, smem + s * 16);
    int ar = s >> 5, asp = s & 31;                      // Vt: 32 slots/row
    gl_lds16(vbase + ar * 256 + (asp ^ (ar & 7)) * 8, smem + 32768 + s * 16);
  }
  bf16v8 qf[2];
#pragma unroll
  for (int kk = 0; kk < 2; ++kk)
    qf[kk] = *(const bf16v8*)(qbase + lane15 * 64 + kk * 32 + g * 8);
  __syncthreads();

  // S = Q K^T : 16 col-tiles x 2 k-steps
  f32x4 sacc[16] = {};
#pragma unroll
  for (int tl = 0; tl < 16; ++tl) {
    int key = tl * 16 + lane15;
    int rb = key * 128, swk = (key & 7) << 4;
#pragma unroll
    for (int kk = 0; kk < 2; ++kk) {
      bf16v8 kf = *(const bf16v8*)(smem + rb + (((kk * 4 + g) * 16) ^ swk));
      sacc[tl] = __builtin_amdgcn_mfma_f32_16x16x32_bf16(qf[kk], kf, sacc[tl], 0, 0, 0);
    }
  }

  // softmax over 256 keys per q-row (rows live on (g, i); cols on lane15 x tile)
  float mx[4], sm[4], rcp[4];
#pragma unroll
  for (int i = 0; i < 4; ++i) mx[i] = sacc[0][i];
#pragma unroll
  for (int tl = 1; tl < 16; ++tl)
#pragma unroll
    for (int i = 0; i < 4; ++i) mx[i] = fmaxf(mx[i], sacc[tl][i]);
#pragma unroll
  for (int i = 0; i < 4; ++i) {
    mx[i] = fmaxf(mx[i], __shfl_xor(mx[i], 1));
    mx[i] = fmaxf(mx[i], __shfl_xor(mx[i], 2));
    mx[i] = fmaxf(mx[i], __shfl_xor(mx[i], 4));
    mx[i] = fmaxf(mx[i], __shfl_xor(mx[i], 8));
    sm[i] = 0.f;
  }
#pragma unroll
  for (int tl = 0; tl < 16; ++tl)
#pragma unroll
    for (int i = 0; i < 4; ++i) {
      float e = __expf((sacc[tl][i] - mx[i]) * 0.125f);
      sacc[tl][i] = e; sm[i] += e;
    }
#pragma unroll
  for (int i = 0; i < 4; ++i) {
    sm[i] += __shfl_xor(sm[i], 1);
    sm[i] += __shfl_xor(sm[i], 2);
    sm[i] += __shfl_xor(sm[i], 4);
    sm[i] += __shfl_xor(sm[i], 8);
    rcp[i] = 1.0f / sm[i];
  }

  // O = P V  (two key-halves through the per-wave P slab)
  char* pbase = smem + 65536 + wave * 4096;
  f32x4 oacc[4] = {};
#pragma unroll
  for (int h2 = 0; h2 < 2; ++h2) {
#pragma unroll
    for (int t8 = 0; t8 < 8; ++t8) {
      int tl = h2 * 8 + t8;
#pragma unroll
      for (int i = 0; i < 4; ++i) {
        int r = g * 4 + i;
        int c2 = t8 * 16 + lane15;
        *(bf16*)(pbase + r * 256 + ((c2 * 2) ^ ((r & 7) << 4))) =
            __float2bfloat16(sacc[tl][i] * rcp[i]);
      }
    }
    asm volatile("" ::: "memory");   // keep ds writes before dependent ds reads
#pragma unroll
    for (int k2 = 0; k2 < 4; ++k2) {
      int ks = h2 * 4 + k2;
      bf16v8 pf = *(const bf16v8*)(pbase + lane15 * 256 +
                                   ((k2 * 64 + g * 16) ^ ((lane15 & 7) << 4)));
#pragma unroll
      for (int at = 0; at < 4; ++at) {
        int a = at * 16 + lane15;
        bf16v8 vf = *(const bf16v8*)(smem + 32768 + a * 512 +
                                     ((ks * 64 + g * 16) ^ ((a & 7) << 4)));
        oacc[at] = __builtin_amdgcn_mfma_f32_16x16x32_bf16(pf, vf, oacc[at], 0, 0, 0);
      }
    }
    asm volatile("" ::: "memory");
  }

  int trow = bm * 256 + qc * 64 + wave * 16;
#pragma unroll
  for (int at = 0; at < 4; ++at)
#pragma unroll
    for (int i = 0; i < 4; ++i)
      z[(size_t)(trow + g * 4 + i) * 512 + hh * 64 + at * 16 + lane15] =
          __float2bfloat16(oacc[at][i]);
}

// ------------------------- layernorm kernels -------------------------
static __device__ __forceinline__ float wredsum(float v) {
  v += __shfl_xor(v, 1);  v += __shfl_xor(v, 2);  v += __shfl_xor(v, 4);
  v += __shfl_xor(v, 8);  v += __shfl_xor(v, 16); v += __shfl_xor(v, 32);
  return v;
}

// z2 = relu(x + LN(y1)*g1 + b1), one row per wave
__global__ __launch_bounds__(256) void ln_res_kernel(const bf16* __restrict__ y1,
                                                     const float* __restrict__ x,
                                                     const float* __restrict__ g1,
                                                     const float* __restrict__ b1,
                                                     bf16* __restrict__ z2) {
  const int wave = threadIdx.x >> 6, lane = threadIdx.x & 63;
  const int row = blockIdx.x * 4 + wave;
  const size_t base = (size_t)row * 512 + lane * 8;
  s16x8 yv = *(const s16x8*)(y1 + base);
  float f[8];
#pragma unroll
  for (int j = 0; j < 8; ++j) f[j] = bfu2f((unsigned short)yv[j]);
  float s = 0.f, s2 = 0.f;
#pragma unroll
  for (int j = 0; j < 8; ++j) { s += f[j]; s2 += f[j] * f[j]; }
  s = wredsum(s); s2 = wredsum(s2);
  float mu = s * (1.f / 512.f);
  float var = s2 * (1.f / 512.f) - mu * mu;
  float rs = rsqrtf(var + 1e-5f);
  float4 x0 = *(const float4*)(x + base);
  float4 x1 = *(const float4*)(x + base + 4);
  float xa[8] = {x0.x, x0.y, x0.z, x0.w, x1.x, x1.y, x1.z, x1.w};
  float ga[8], ba[8];
#pragma unroll
  for (int j = 0; j < 8; ++j) { ga[j] = g1[lane * 8 + j]; ba[j] = b1[lane * 8 + j]; }
  s16x8 ov;
#pragma unroll
  for (int j = 0; j < 8; ++j) {
    float v = xa[j] + (f[j] - mu) * rs * ga[j] + ba[j];
    ov[j] = (short)f2bfu(fmaxf(v, 0.f));
  }
  *(s16x8*)(z2 + base) = ov;
}

// out = relu(LN(y2)*g2 + b2), f32 in/out, one row per wave
__global__ __launch_bounds__(256) void ln_out_kernel(const float* __restrict__ y2,
                                                     const float* __restrict__ g2,
                                                     const float* __restrict__ b2,
                                                     float* __restrict__ out) {
  const int wave = threadIdx.x >> 6, lane = threadIdx.x & 63;
  const int row = blockIdx.x * 4 + wave;
  const size_t base = (size_t)row * 512 + lane * 8;
  float4 v0 = *(const float4*)(y2 + base);
  float4 v1 = *(const float4*)(y2 + base + 4);
  float f[8] = {v0.x, v0.y, v0.z, v0.w, v1.x, v1.y, v1.z, v1.w};
  float s = 0.f, s2 = 0.f;
#pragma unroll
  for (int j = 0; j < 8; ++j) { s += f[j]; s2 += f[j] * f[j]; }
  s = wredsum(s); s2 = wredsum(s2);
  float mu = s * (1.f / 512.f);
  float var = s2 * (1.f / 512.f) - mu * mu;
  float rs = rsqrtf(var + 1e-5f);
  float o[8];
#pragma unroll
  for (int j = 0; j < 8; ++j)
    o[j] = fmaxf((f[j] - mu) * rs * g2[lane * 8 + j] + b2[lane * 8 + j], 0.f);
  float4 w0 = {o[0], o[1], o[2], o[3]};
  float4 w1 = {o[4], o[5], o[6], o[7]};
  *(float4*)(out + base) = w0;
  *(float4*)(out + base + 4) = w1;
}

// ------------------------- launch -------------------------
extern "C" void kernel_launch(void* const* d_in, const int* in_sizes, int n_in,
                              void* d_out, int out_size, void* d_ws, size_t ws_size,
                              hipStream_t stream) {
  const float* x  = (const float*)d_in[0];
  const float* Wq = (const float*)d_in[1];
  const float* bq = (const float*)d_in[2];
  const float* Wk = (const float*)d_in[3];
  const float* bk = (const float*)d_in[4];
  const float* Wv = (const float*)d_in[5];
  const float* bv = (const float*)d_in[6];
  const float* Wo = (const float*)d_in[7];
  const float* bo = (const float*)d_in[8];
  const float* g1 = (const float*)d_in[9];
  const float* b1 = (const float*)d_in[10];
  const float* Wd = (const float*)d_in[11];
  const float* bd = (const float*)d_in[12];
  const float* g2 = (const float*)d_in[13];
  const float* b2 = (const float*)d_in[14];

  char* ws = (char*)d_ws;
  const size_t SEG = 50331648;
  bf16*  xb   = (bf16*)(ws);                       // x bf16 -> later z
  bf16*  qb   = (bf16*)(ws + SEG);                 // q      -> later y1
  bf16*  kb   = (bf16*)(ws + 2 * SEG);             // k      -> later z2
  bf16*  vtb  = (bf16*)(ws + 3 * SEG);             // v^T    -> later y2 (f32)
  bf16*  wqkv = (bf16*)(ws + 4 * SEG);
  bf16*  wot  = (bf16*)(ws + 4 * SEG + 1572864);
  bf16*  wdt  = (bf16*)(ws + 4 * SEG + 2097152);
  float* bqkv = (float*)(ws + 4 * SEG + 3145728);
  bf16*  zb   = xb;
  bf16*  y1   = qb;
  bf16*  z2   = kb;
  float* y2   = (float*)vtb;

  conv_x_kernel<<<4096, 256, 0, stream>>>((const float4*)x, (s16x4*)xb, 25165824 / 4);
  conv_w_kernel<<<6150, 256, 0, stream>>>(Wq, Wk, Wv, Wo, Wd, bq, bk, bv,
                                          wqkv, wot, wdt, bqkv);
  gemm256<0, 0><<<dim3(192, 6), 512, 0, stream>>>(xb, wqkv, bqkv, 512,
                                                  qb, kb, vtb, nullptr, nullptr);
  attn_kernel<<<dim3(4, 8, 192), 256, 0, stream>>>(qb, kb, vtb, zb);
  gemm256<1, 0><<<dim3(192, 2), 512, 0, stream>>>(zb, wot, bo, 512,
                                                  nullptr, nullptr, nullptr, y1, nullptr);
  ln_res_kernel<<<12288, 256, 0, stream>>>(y1, x, g1, b1, z2);
  gemm256<2, 1><<<dim3(96, 2), 512, 0, stream>>>(z2, wdt, bd, 1024,
                                                 nullptr, nullptr, nullptr, nullptr, y2);
  ln_out_kernel<<<6144, 256, 0, stream>>>(y2, g2, b2, (float*)d_out);
}

// Round 4
// 337.610 us; speedup vs baseline: 1.2080x; 1.0330x over previous
//
#include <hip/hip_runtime.h>
#include <hip/hip_bf16.h>
#include <stdint.h>

// VisionTransformerBlock on MI355X (gfx950).
// Pipeline: conv(x,W->bf16) -> QKV gemm -> attention -> Wo gemm -> LN1+res+relu
//           -> merged Wd gemm -> LN2+relu -> d_out (f32).
// GEMM: 256x256 tile, BK=64, 8 waves, 8-phase with MINIMAL barriers (4/iter):
//   barriers only at end of p2/p3/p6/p7, lgkmcnt(0) before each so no wave
//   crosses with reads outstanding; vmcnt(4) only at p3/p7. Between barriers
//   waves free-run (ds_read/MFMA overlap across waves).
// Epilogues: per-wave 16KB LDS slab transpose -> coalesced b128 stores.

typedef __hip_bfloat16 bf16;
typedef __attribute__((ext_vector_type(8))) __bf16 bf16v8;
typedef __attribute__((ext_vector_type(4))) float f32x4;
typedef __attribute__((ext_vector_type(8))) short s16x8;
typedef __attribute__((ext_vector_type(4))) short s16x4;

static __device__ __forceinline__ void gl_lds16(const void* src, void* dst) {
  __builtin_amdgcn_global_load_lds((const __attribute__((address_space(1))) void*)src,
                                   (__attribute__((address_space(3))) void*)dst,
                                   16, 0, 0);
}

static __device__ __forceinline__ unsigned short f2bfu(float f) {
  return __builtin_bit_cast(unsigned short, __float2bfloat16(f));
}
static __device__ __forceinline__ float bfu2f(unsigned short u) {
  return __builtin_bit_cast(float, (unsigned int)u << 16);
}

// ------------------------- conversions -------------------------
__global__ __launch_bounds__(256) void conv_x_kernel(const float4* __restrict__ x,
                                                     s16x4* __restrict__ xb, int n4) {
  int stride = gridDim.x * 256;
  for (int i = blockIdx.x * 256 + threadIdx.x; i < n4; i += stride) {
    float4 v = x[i];
    s16x4 o;
    o[0] = (short)f2bfu(v.x); o[1] = (short)f2bfu(v.y);
    o[2] = (short)f2bfu(v.z); o[3] = (short)f2bfu(v.w);
    xb[i] = o;
  }
}

__global__ __launch_bounds__(256) void conv_w_kernel(
    const float* __restrict__ Wq, const float* __restrict__ Wk, const float* __restrict__ Wv,
    const float* __restrict__ Wo, const float* __restrict__ Wd,
    const float* __restrict__ bq, const float* __restrict__ bk, const float* __restrict__ bv,
    bf16* __restrict__ wqkv_t, bf16* __restrict__ wo_t, bf16* __restrict__ wd_t,
    float* __restrict__ bqkv) {
  int o = blockIdx.x * 256 + threadIdx.x;
  if (o < 786432) {                       // wqkv_t[j][kk], j in [0,1536)
    int j = o >> 9, kk = o & 511;
    const float* W = (j < 512) ? Wq : (j < 1024) ? Wk : Wv;
    wqkv_t[o] = __float2bfloat16(W[kk * 512 + (j & 511)]);
  } else if (o < 1048576) {               // wo_t[j][kk]
    int o2 = o - 786432; int j = o2 >> 9, kk = o2 & 511;
    wo_t[o2] = __float2bfloat16(Wo[kk * 512 + j]);
  } else if (o < 1572864) {               // wd_t[j][kk], kk in [0,1024)
    int o3 = o - 1048576; int j = o3 >> 10, kk = o3 & 1023;
    wd_t[o3] = __float2bfloat16(Wd[kk * 512 + j]);
  } else if (o < 1574400) {               // bqkv concat (f32)
    int o4 = o - 1572864;
    const float* b = (o4 < 512) ? bq : (o4 < 1024) ? bk : bv;
    bqkv[o4] = b[o4 & 511];
  }
}

// ------------------------- GEMM 256x256, BK=64 -------------------------
// A: bf16 row-major [M][K] (AMODE1: patch-merged view of z2 [49152][512]).
// Bt: bf16 [N][K]. LDS: 2 buffers x (A[256][64] + B[256][64]) = 128 KB.
// Row layout: 8 x 16B slots, physical slot = logical_chunk ^ (row&7)
// (inverse swizzle on the global source; global_load_lds dest linear).
// Iteration i: tile 2i in buf0 (p0-3), tile 2i+1 in buf1 (p4-7).
// Stage: p0:B(2i+1), p3:A(2i+2), p4:B(2i+2), p7:A(2i+3).
// Hazard ledger (stage-after-read): buf1.B last read p7' -> barrier end-p7';
// buf0.A last read p2 -> barrier end-p2; buf0.B last read p3 -> end-p3;
// buf1.A last read p6 -> end-p6. (read-after-stage): tile 2i+1 landed by
// vmcnt(4)@p3 + barrier; tile 2i+2 by vmcnt(4)@p7 + barrier. lgkmcnt(0)
// before every barrier so no wave's ds_reads are outstanding across it.
// EPI 0: qkv scatter (LDS slab transpose); 1: bf16 row-major out, ldc=512.
template<int EPI, int AMODE>
__global__ __launch_bounds__(512, 2) void gemm256(
    const bf16* __restrict__ A, const bf16* __restrict__ Bt,
    const float* __restrict__ bias, int K,
    bf16* __restrict__ oq, bf16* __restrict__ ok, bf16* __restrict__ ovt,
    bf16* __restrict__ obf) {
  __shared__ __align__(16) char smem[131072];
  const int tid = threadIdx.x;
  const int wave = tid >> 6, lane = tid & 63;
  const int wr = wave >> 2, wc = wave & 3;         // 2M x 4N waves
  const int lane15 = lane & 15, g = lane >> 4;
  const int tileM = blockIdx.x * 256, tileN = blockIdx.y * 256;

  const int rT = tid >> 3;                 // row within half (j=0), +64 for j=1
  const int cT = (tid & 7) ^ (rT & 7);     // inverse-swizzled logical chunk

  const int iters = K >> 7;                // 2 K-tiles (BK=64) per iteration

  auto stage = [&](int tau, int q) {       // q: 0 A.h0, 1 A.h1, 2 B.h0, 3 B.h1
    char* dst = smem + ((tau & 1) << 16) + ((q >> 1) << 15) + ((q & 1) << 14) + tid * 16;
    int kpos = tau * 64 + cT * 8;
    if (q < 2) {
      int rowA = tileM + ((q & 1) << 7) + rT;
      if (AMODE == 0) {
        const bf16* s0 = A + (size_t)rowA * K + kpos;
        gl_lds16(s0, dst);
        gl_lds16(s0 + (size_t)64 * K, dst + 8192);
      } else {
#pragma unroll
        for (int j = 0; j < 2; ++j) {
          int mr = rowA + j * 64;
          int bm = mr >> 7, pp = mr & 127;
          const bf16* s = A + (size_t)(bm * 256 + pp * 2 + (kpos >> 9)) * 512 + (kpos & 511);
          gl_lds16(s, dst + j * 8192);
        }
      }
    } else {
      int rowB = tileN + ((q & 1) << 7) + rT;
      const bf16* s0 = Bt + (size_t)rowB * K + kpos;
      gl_lds16(s0, dst);
      gl_lds16(s0 + (size_t)64 * K, dst + 8192);
    }
  };

  f32x4 acc[8][4] = {};
  bf16v8 areg[4][2], breg[2][2];

  // prologue: tile 0 fully + A(1) halves (12 vmcnt ops)
  stage(0, 0); stage(0, 1); stage(0, 2); stage(0, 3);
  stage(1, 0); stage(1, 1);
  asm volatile("s_waitcnt vmcnt(4)" ::: "memory");   // tile 0 landed
  __builtin_amdgcn_s_barrier();

  for (int it = 0; it < iters; ++it) {
    const bool last = (it == iters - 1);
#pragma unroll
    for (int p = 0; p < 8; ++p) {
      const int buf = p >> 2;
      const int mh = (p >> 1) & 1, nh = p & 1;
      char* Ab = smem + (buf << 16);
      char* Bb = Ab + 32768;
      if (nh == 0) {
#pragma unroll
        for (int f = 0; f < 4; ++f) {
          int row = wr * 128 + (mh * 4 + f) * 16 + lane15;
#pragma unroll
          for (int ks = 0; ks < 2; ++ks)
            areg[f][ks] = *(const bf16v8*)(Ab + row * 128 + (((ks * 4 + g) ^ (row & 7)) << 4));
        }
      }
#pragma unroll
      for (int n = 0; n < 2; ++n) {
        int row = wc * 64 + (nh * 2 + n) * 16 + lane15;
#pragma unroll
        for (int ks = 0; ks < 2; ++ks)
          breg[n][ks] = *(const bf16v8*)(Bb + row * 128 + (((ks * 4 + g) ^ (row & 7)) << 4));
      }
      // staging (region freed by the barrier that just preceded this phase)
      if (p == 0)      { stage(2 * it + 1, 2); stage(2 * it + 1, 3); }
      else if (p == 3) { if (!last) { stage(2 * it + 2, 0); stage(2 * it + 2, 1); } }
      else if (p == 4) { if (!last) { stage(2 * it + 2, 2); stage(2 * it + 2, 3); } }
      else if (p == 7) { if (!last) { stage(2 * it + 3, 0); stage(2 * it + 3, 1); } }
      __builtin_amdgcn_s_setprio(1);
#pragma unroll
      for (int ks = 0; ks < 2; ++ks)
#pragma unroll
        for (int f = 0; f < 4; ++f)
#pragma unroll
          for (int n = 0; n < 2; ++n)
            acc[mh * 4 + f][nh * 2 + n] = __builtin_amdgcn_mfma_f32_16x16x32_bf16(
                areg[f][ks], breg[n][ks], acc[mh * 4 + f][nh * 2 + n], 0, 0, 0);
      __builtin_amdgcn_s_setprio(0);
      // sync points (4 barriers per iteration)
      if (p == 2 || p == 6) {
        asm volatile("s_waitcnt lgkmcnt(0)" ::: "memory");
        __builtin_amdgcn_s_barrier();
      } else if (p == 3) {
        if (last) { asm volatile("s_waitcnt vmcnt(0) lgkmcnt(0)" ::: "memory"); }
        else      { asm volatile("s_waitcnt vmcnt(4) lgkmcnt(0)" ::: "memory"); }
        __builtin_amdgcn_s_barrier();
      } else if (p == 7) {
        if (last) { asm volatile("s_waitcnt lgkmcnt(0)" ::: "memory"); }
        else      { asm volatile("s_waitcnt vmcnt(4) lgkmcnt(0)" ::: "memory"); }
        __builtin_amdgcn_s_barrier();
      }
    }
  }

  // ------------------------- epilogue (per-wave LDS slab) -------------------------
  if (EPI == 0 && tileN >= 1024) {
    // v-block: slab [64 a][128 p] swizzled -> coalesced stores to vt[bh][a][p]
    const int hh = ((tileN - 1024) >> 6) + wc;
    const int bm = tileM >> 8;
    char* slab = smem + wave * 16384;
#pragma unroll
    for (int fm = 0; fm < 8; ++fm) {
#pragma unroll
      for (int fn = 0; fn < 4; ++fn) {
        int col = tileN + wc * 64 + fn * 16 + lane15;
        float bb = bias[col];
        int a = fn * 16 + lane15;
#pragma unroll
        for (int i = 0; i < 4; ++i) {
          int pl = fm * 16 + g * 4 + i;
          *(bf16*)(slab + a * 256 + ((pl * 2) ^ ((a & 7) << 4))) =
              __float2bfloat16(acc[fm][fn][i] + bb);
        }
      }
    }
    asm volatile("" ::: "memory");
    bf16* vdst = ovt + ((size_t)(bm * 8 + hh) << 14) + wr * 128;
#pragma unroll
    for (int r = 0; r < 16; ++r) {
      int a = r * 4 + (lane >> 4);
      int ps = lane & 15;
      s16x8 vv = *(const s16x8*)(slab + a * 256 + ((ps * 16) ^ ((a & 7) << 4)));
      *(s16x8*)(vdst + a * 256 + ps * 8) = vv;
    }
  } else {
    // q/k (EPI0) and row-major bf16 (EPI1): slab [128 p][64 a] (32B-XOR swz)
    char* slab = smem + wave * 16384;
#pragma unroll
    for (int fm = 0; fm < 8; ++fm) {
#pragma unroll
      for (int fn = 0; fn < 4; ++fn) {
        int col = tileN + wc * 64 + fn * 16 + lane15;
        float bb = bias[col];
        int lb = (fn * 16 + lane15) * 2;
#pragma unroll
        for (int i = 0; i < 4; ++i) {
          int pl = fm * 16 + g * 4 + i;
          *(bf16*)(slab + pl * 128 + (lb ^ ((((pl >> 2) & 3)) << 5))) =
              __float2bfloat16(acc[fm][fn][i] + bb);
        }
      }
    }
    asm volatile("" ::: "memory");
    bf16* dst; int ldc2;
    if (EPI == 0) {
      int cb = tileN + wc * 64;
      int hh = (cb >> 6) & 7;
      bf16* base = (cb < 512) ? oq : ok;
      dst = base + (((size_t)((tileM >> 8) * 8 + hh)) << 14) + wr * 128 * 64;
      ldc2 = 64;
    } else {
      dst = obf + (size_t)(tileM + wr * 128) * 512 + tileN + wc * 64;
      ldc2 = 512;
    }
#pragma unroll
    for (int r = 0; r < 16; ++r) {
      int s = r * 64 + lane;
      int pl = s >> 3, sl = s & 7;
      s16x8 vv = *(const s16x8*)(slab + pl * 128 + ((sl * 16) ^ ((((pl >> 2) & 3)) << 5)));
      *(s16x8*)(dst + (size_t)pl * ldc2 + sl * 8) = vv;
    }
  }
}

// ------------------------- attention -------------------------
// Block = (qc, h, bm): 64 q-rows, 4 waves x 16 rows. LDS: K[256][64] (swz),
// Vt[64][256] (swz), P per-wave 16x128 bf16 round-trip slab (swz). 80 KB.
__global__ __launch_bounds__(256) void attn_kernel(const bf16* __restrict__ q,
                                                   const bf16* __restrict__ k,
                                                   const bf16* __restrict__ vt,
                                                   bf16* __restrict__ z) {
  __shared__ __align__(16) char smem[81920];
  const int tid = threadIdx.x, wave = tid >> 6, lane = tid & 63;
  const int lane15 = lane & 15, g = lane >> 4;
  const int qc = blockIdx.x, hh = blockIdx.y, bm = blockIdx.z;
  const int bh = bm * 8 + hh;
  const bf16* kbase = k + ((size_t)bh << 14);
  const bf16* vbase = vt + ((size_t)bh << 14);
  const bf16* qbase = q + ((size_t)bh << 14) + (qc * 64 + wave * 16) * 64;

#pragma unroll
  for (int i = 0; i < 8; ++i) {
    int s = i * 256 + tid;
    int kr = s >> 3, ksp = s & 7;                       // K: 8 slots/row
    gl_lds16(kbase + kr * 64 + (ksp ^ (kr & 7)) * 8, smem + s * 16);
    int ar = s >> 5, asp = s & 31;                      // Vt: 32 slots/row
    gl_lds16(vbase + ar * 256 + (asp ^ (ar & 7)) * 8, smem + 32768 + s * 16);
  }
  bf16v8 qf[2];
#pragma unroll
  for (int kk = 0; kk < 2; ++kk)
    qf[kk] = *(const bf16v8*)(qbase + lane15 * 64 + kk * 32 + g * 8);
  __syncthreads();

  // S = Q K^T : 16 col-tiles x 2 k-steps
  f32x4 sacc[16] = {};
#pragma unroll
  for (int tl = 0; tl < 16; ++tl) {
    int key = tl * 16 + lane15;
    int rb = key * 128, swk = (key & 7) << 4;
#pragma unroll
    for (int kk = 0; kk < 2; ++kk) {
      bf16v8 kf = *(const bf16v8*)(smem + rb + (((kk * 4 + g) * 16) ^ swk));
      sacc[tl] = __builtin_amdgcn_mfma_f32_16x16x32_bf16(qf[kk], kf, sacc[tl], 0, 0, 0);
    }
  }

  // softmax over 256 keys per q-row
  float mx[4], sm[4], rcp[4];
#pragma unroll
  for (int i = 0; i < 4; ++i) mx[i] = sacc[0][i];
#pragma unroll
  for (int tl = 1; tl < 16; ++tl)
#pragma unroll
    for (int i = 0; i < 4; ++i) mx[i] = fmaxf(mx[i], sacc[tl][i]);
#pragma unroll
  for (int i = 0; i < 4; ++i) {
    mx[i] = fmaxf(mx[i], __shfl_xor(mx[i], 1));
    mx[i] = fmaxf(mx[i], __shfl_xor(mx[i], 2));
    mx[i] = fmaxf(mx[i], __shfl_xor(mx[i], 4));
    mx[i] = fmaxf(mx[i], __shfl_xor(mx[i], 8));
    sm[i] = 0.f;
  }
#pragma unroll
  for (int tl = 0; tl < 16; ++tl)
#pragma unroll
    for (int i = 0; i < 4; ++i) {
      float e = __expf((sacc[tl][i] - mx[i]) * 0.125f);
      sacc[tl][i] = e; sm[i] += e;
    }
#pragma unroll
  for (int i = 0; i < 4; ++i) {
    sm[i] += __shfl_xor(sm[i], 1);
    sm[i] += __shfl_xor(sm[i], 2);
    sm[i] += __shfl_xor(sm[i], 4);
    sm[i] += __shfl_xor(sm[i], 8);
    rcp[i] = 1.0f / sm[i];
  }

  // O = P V  (two key-halves through the per-wave P slab)
  char* pbase = smem + 65536 + wave * 4096;
  f32x4 oacc[4] = {};
#pragma unroll
  for (int h2 = 0; h2 < 2; ++h2) {
#pragma unroll
    for (int t8 = 0; t8 < 8; ++t8) {
      int tl = h2 * 8 + t8;
#pragma unroll
      for (int i = 0; i < 4; ++i) {
        int r = g * 4 + i;
        int c2 = t8 * 16 + lane15;
        *(bf16*)(pbase + r * 256 + ((c2 * 2) ^ ((r & 7) << 4))) =
            __float2bfloat16(sacc[tl][i] * rcp[i]);
      }
    }
    asm volatile("" ::: "memory");
#pragma unroll
    for (int k2 = 0; k2 < 4; ++k2) {
      int ks = h2 * 4 + k2;
      bf16v8 pf = *(const bf16v8*)(pbase + lane15 * 256 +
                                   ((k2 * 64 + g * 16) ^ ((lane15 & 7) << 4)));
#pragma unroll
      for (int at = 0; at < 4; ++at) {
        int a = at * 16 + lane15;
        bf16v8 vf = *(const bf16v8*)(smem + 32768 + a * 512 +
                                     ((ks * 64 + g * 16) ^ ((a & 7) << 4)));
        oacc[at] = __builtin_amdgcn_mfma_f32_16x16x32_bf16(pf, vf, oacc[at], 0, 0, 0);
      }
    }
    asm volatile("" ::: "memory");
  }

  int trow = bm * 256 + qc * 64 + wave * 16;
#pragma unroll
  for (int at = 0; at < 4; ++at)
#pragma unroll
    for (int i = 0; i < 4; ++i)
      z[(size_t)(trow + g * 4 + i) * 512 + hh * 64 + at * 16 + lane15] =
          __float2bfloat16(oacc[at][i]);
}

// ------------------------- layernorm kernels -------------------------
static __device__ __forceinline__ float wredsum(float v) {
  v += __shfl_xor(v, 1);  v += __shfl_xor(v, 2);  v += __shfl_xor(v, 4);
  v += __shfl_xor(v, 8);  v += __shfl_xor(v, 16); v += __shfl_xor(v, 32);
  return v;
}

// z2 = relu(x + LN(y1)*g1 + b1), one row per wave
__global__ __launch_bounds__(256) void ln_res_kernel(const bf16* __restrict__ y1,
                                                     const float* __restrict__ x,
                                                     const float* __restrict__ g1,
                                                     const float* __restrict__ b1,
                                                     bf16* __restrict__ z2) {
  const int wave = threadIdx.x >> 6, lane = threadIdx.x & 63;
  const int row = blockIdx.x * 4 + wave;
  const size_t base = (size_t)row * 512 + lane * 8;
  s16x8 yv = *(const s16x8*)(y1 + base);
  float f[8];
#pragma unroll
  for (int j = 0; j < 8; ++j) f[j] = bfu2f((unsigned short)yv[j]);
  float s = 0.f, s2 = 0.f;
#pragma unroll
  for (int j = 0; j < 8; ++j) { s += f[j]; s2 += f[j] * f[j]; }
  s = wredsum(s); s2 = wredsum(s2);
  float mu = s * (1.f / 512.f);
  float var = s2 * (1.f / 512.f) - mu * mu;
  float rs = rsqrtf(var + 1e-5f);
  float4 x0 = *(const float4*)(x + base);
  float4 x1 = *(const float4*)(x + base + 4);
  float xa[8] = {x0.x, x0.y, x0.z, x0.w, x1.x, x1.y, x1.z, x1.w};
  float ga[8], ba[8];
#pragma unroll
  for (int j = 0; j < 8; ++j) { ga[j] = g1[lane * 8 + j]; ba[j] = b1[lane * 8 + j]; }
  s16x8 ov;
#pragma unroll
  for (int j = 0; j < 8; ++j) {
    float v = xa[j] + (f[j] - mu) * rs * ga[j] + ba[j];
    ov[j] = (short)f2bfu(fmaxf(v, 0.f));
  }
  *(s16x8*)(z2 + base) = ov;
}

// out = relu(LN(y2)*g2 + b2), bf16 in, f32 out, one row per wave
__global__ __launch_bounds__(256) void ln_out_kernel(const bf16* __restrict__ y2,
                                                     const float* __restrict__ g2,
                                                     const float* __restrict__ b2,
                                                     float* __restrict__ out) {
  const int wave = threadIdx.x >> 6, lane = threadIdx.x & 63;
  const int row = blockIdx.x * 4 + wave;
  const size_t base = (size_t)row * 512 + lane * 8;
  s16x8 yv = *(const s16x8*)(y2 + base);
  float f[8];
#pragma unroll
  for (int j = 0; j < 8; ++j) f[j] = bfu2f((unsigned short)yv[j]);
  float s = 0.f, s2 = 0.f;
#pragma unroll
  for (int j = 0; j < 8; ++j) { s += f[j]; s2 += f[j] * f[j]; }
  s = wredsum(s); s2 = wredsum(s2);
  float mu = s * (1.f / 512.f);
  float var = s2 * (1.f / 512.f) - mu * mu;
  float rs = rsqrtf(var + 1e-5f);
  float o[8];
#pragma unroll
  for (int j = 0; j < 8; ++j)
    o[j] = fmaxf((f[j] - mu) * rs * g2[lane * 8 + j] + b2[lane * 8 + j], 0.f);
  float4 w0 = {o[0], o[1], o[2], o[3]};
  float4 w1 = {o[4], o[5], o[6], o[7]};
  *(float4*)(out + base) = w0;
  *(float4*)(out + base + 4) = w1;
}

// ------------------------- launch -------------------------
extern "C" void kernel_launch(void* const* d_in, const int* in_sizes, int n_in,
                              void* d_out, int out_size, void* d_ws, size_t ws_size,
                              hipStream_t stream) {
  const float* x  = (const float*)d_in[0];
  const float* Wq = (const float*)d_in[1];
  const float* bq = (const float*)d_in[2];
  const float* Wk = (const float*)d_in[3];
  const float* bk = (const float*)d_in[4];
  const float* Wv = (const float*)d_in[5];
  const float* bv = (const float*)d_in[6];
  const float* Wo = (const float*)d_in[7];
  const float* bo = (const float*)d_in[8];
  const float* g1 = (const float*)d_in[9];
  const float* b1 = (const float*)d_in[10];
  const float* Wd = (const float*)d_in[11];
  const float* bd = (const float*)d_in[12];
  const float* g2 = (const float*)d_in[13];
  const float* b2 = (const float*)d_in[14];

  char* ws = (char*)d_ws;
  const size_t SEG = 50331648;
  bf16*  xb   = (bf16*)(ws);                       // x bf16 -> later z
  bf16*  qb   = (bf16*)(ws + SEG);                 // q      -> later y1
  bf16*  kb   = (bf16*)(ws + 2 * SEG);             // k      -> later z2
  bf16*  vtb  = (bf16*)(ws + 3 * SEG);             // v^T    -> later y2 (bf16)
  bf16*  wqkv = (bf16*)(ws + 4 * SEG);
  bf16*  wot  = (bf16*)(ws + 4 * SEG + 1572864);
  bf16*  wdt  = (bf16*)(ws + 4 * SEG + 2097152);
  float* bqkv = (float*)(ws + 4 * SEG + 3145728);
  bf16*  zb   = xb;
  bf16*  y1   = qb;
  bf16*  z2   = kb;
  bf16*  y2   = vtb;

  conv_x_kernel<<<4096, 256, 0, stream>>>((const float4*)x, (s16x4*)xb, 25165824 / 4);
  conv_w_kernel<<<6150, 256, 0, stream>>>(Wq, Wk, Wv, Wo, Wd, bq, bk, bv,
                                          wqkv, wot, wdt, bqkv);
  gemm256<0, 0><<<dim3(192, 6), 512, 0, stream>>>(xb, wqkv, bqkv, 512,
                                                  qb, kb, vtb, nullptr);
  attn_kernel<<<dim3(4, 8, 192), 256, 0, stream>>>(qb, kb, vtb, zb);
  gemm256<1, 0><<<dim3(192, 2), 512, 0, stream>>>(zb, wot, bo, 512,
                                                  nullptr, nullptr, nullptr, y1);
  ln_res_kernel<<<12288, 256, 0, stream>>>(y1, x, g1, b1, z2);
  gemm256<1, 1><<<dim3(96, 2), 512, 0, stream>>>(z2, wdt, bd, 1024,
                                                 nullptr, nullptr, nullptr, y2);
  ln_out_kernel<<<6144, 256, 0, stream>>>(y2, g2, b2, (float*)d_out);
}